// Round 5
// baseline (429.576 us; speedup 1.0000x reference)
//
#include <hip/hip_runtime.h>

typedef __attribute__((ext_vector_type(4))) unsigned int u32x4;
typedef __attribute__((ext_vector_type(4))) int i32x4;

union I16 { u32x4 u; i32x4 i; };

#define SA_INV   (127.0f / 12.0f)           // a = -2z, |a| <= 12 (z tail ~5.2)
#define SB_INV   (127.0f * 8192.0f)         // b in [-1/8192, 1/8192]
#define INV_SASB ((127.0 * 127.0 * 8192.0) / 12.0)   // 1/(sa*sb) ~ 1.101e7
#define WI       4500                        // refine window in int units (~4e-4)
#define FINF     3.4e38f

__device__ __forceinline__ int q8(float x, float s) {
    int q = (int)__builtin_rintf(x * s);
    return q < -127 ? -127 : (q > 127 ? 127 : q);
}
__device__ __forceinline__ unsigned int umin(unsigned int a, unsigned int b) { return a < b ? a : b; }
__device__ __forceinline__ unsigned int umax(unsigned int a, unsigned int b) { return a > b ? a : b; }

// ---------------------------------------------------------------------------
// prep_z: one pass over z -> (1) i8 A fragments (a=-2z quantized),
// (2) zt row-major [16384][256], (3) z2f (f64-accum sum z^2 -> f32).
// Block = one (b,h) pair; 32x257 LDS transpose tile.
// A-layout (R4-verified): lane l of row-tile rt, k-step j holds
// A[rt*16+(l&15)][k = j*64 + (l>>4)*16 .. +16], bytes LE = increasing k.
// ---------------------------------------------------------------------------
__global__ __launch_bounds__(256)
void prep_z(const float* __restrict__ z, u32x4* __restrict__ ahi,
            float* __restrict__ zt, float* __restrict__ z2f) {
    __shared__ float tile[32][257];
    __shared__ double pz[32][9];
    int bh = blockIdx.x;                          // 0..511 = b*32+h
    int b = bh >> 5, h = bh & 31;
    int tid = threadIdx.x;
    for (int e = tid; e < 8192; e += 256) {
        int d = e >> 5, w = e & 31;
        tile[w][d] = z[((size_t)(b * 256 + d) * 32 + h) * 32 + w];
    }
    __syncthreads();
    // zt (coalesced row-major writes)
    for (int e = tid; e < 8192; e += 256) {
        int w = e >> 8, d = e & 255;
        zt[(size_t)(bh * 32 + w) * 256 + d] = tile[w][d];
    }
    // z2 partials (f64)
    {
        int w = tid >> 3, seg = tid & 7;
        double s = 0.0;
#pragma unroll
        for (int d = 0; d < 32; ++d) { double v = (double)tile[w][seg * 32 + d]; s += v * v; }
        pz[w][seg] = s;
    }
    __syncthreads();
    if (tid < 32) {
        double s = 0.0;
#pragma unroll
        for (int seg = 0; seg < 8; ++seg) s += pz[tid][seg];
        z2f[bh * 32 + tid] = (float)s;
    }
    // i8 A fragments: 512 u32x4 per block (2 row-tiles x 4 j x 64 lanes)
    for (int o = tid; o < 512; o += 256) {
        int l = o & 63, j = (o >> 6) & 3, tt = o >> 8;
        int wp = tt * 16 + (l & 15);
        int k0 = j * 64 + ((l >> 4) << 4);
        u32x4 v;
#pragma unroll
        for (int d = 0; d < 4; ++d) {
            unsigned int wv = 0;
#pragma unroll
            for (int bb = 0; bb < 4; ++bb) {
                int q = q8(-2.0f * tile[wp][k0 + d * 4 + bb], SA_INV);
                wv |= ((unsigned int)(q & 255)) << (8 * bb);
            }
            v[d] = wv;
        }
        ahi[(size_t)bh * 512 + o] = v;
    }
}

// ---------------------------------------------------------------------------
// prep_cb: one pass over codebook -> (1) i8 B fragments in stream order,
// (2) c2 (f32), (3) ibt key-bias table. Block = one 16-code tile.
// Stream layout (chunk = 128 codes): bstr[(stripe*4+ch)*2048 + (t*4+j)*64 + l]
// where code = stripe*512 + ch*128 + t*16 + (l&15), k = j*64+(l>>4)*16..+16.
// ---------------------------------------------------------------------------
__global__ __launch_bounds__(256)
void prep_cb(const float* __restrict__ cb, float* __restrict__ c2,
             unsigned int* __restrict__ ibt, u32x4* __restrict__ bstr) {
    __shared__ float tile[16][257];
    __shared__ float pc[16][17];
    int ct = blockIdx.x;                          // 0..511
    int tid = threadIdx.x;
    int cl = tid >> 4, dseg = tid & 15;
    const float* src = cb + (size_t)(ct * 16 + cl) * 256 + dseg * 16;
    float s = 0.f;
#pragma unroll
    for (int i = 0; i < 16; ++i) { float v = src[i]; tile[cl][dseg * 16 + i] = v; s += v * v; }
    pc[cl][dseg] = s;
    __syncthreads();
    if (tid < 16) {
        float t = 0.f;
#pragma unroll
        for (int i = 0; i < 16; ++i) t += pc[tid][i];
        int code = ct * 16 + tid;
        c2[code] = t;
        int ib = (int)__builtin_rintf(t * (float)INV_SASB);
        ibt[code] = (((unsigned int)(ib + 262144)) << 6) | (unsigned int)((code >> 4) & 31);
    }
    int l = tid & 63, j = tid >> 6;
    int code_l = l & 15, k0 = j * 64 + ((l >> 4) << 4);
    u32x4 v;
#pragma unroll
    for (int d = 0; d < 4; ++d) {
        unsigned int wv = 0;
#pragma unroll
        for (int bb = 0; bb < 4; ++bb) {
            int q = q8(tile[code_l][k0 + d * 4 + bb], SB_INV);
            wv |= ((unsigned int)(q & 255)) << (8 * bb);
        }
        v[d] = wv;
    }
    int stripe = ct >> 5, rr = ct & 31, ch = rr >> 3, t_in = rr & 7;
    bstr[(size_t)(stripe * 4 + ch) * 2048 + (t_in * 4 + j) * 64 + l] = v;
}

// ---------------------------------------------------------------------------
// vq_main: 1024 blocks = 64 rowgroups x 16 stripes. Wave holds 64 rows of i8
// A (64 VGPRs); stripe = 512 codes in 4 chunks of 128 (2x32KB LDS dbuf,
// fully unrolled -> immediate-offset addressing). key=((acc+bias+2^18)<<6)|tc
// via one lshl_add; top-2 via min + med3 (3 VALU/value). launch_bounds(256,2)
// gives a 256-VGPR budget so ah/m1/m2 stay in architectural VGPRs (R4's 120-
// VGPR allocation forced AGPR shuttling = the VALU bloat).
// ---------------------------------------------------------------------------
typedef __attribute__((address_space(1))) unsigned int gu32;
typedef __attribute__((address_space(3))) unsigned int lu32;

__global__ __launch_bounds__(256, 2)
void vq_main(const u32x4* __restrict__ ahi4, const u32x4* __restrict__ bstr,
             const unsigned int* __restrict__ ibt,
             unsigned int* __restrict__ cd, int* __restrict__ ci) {
    __shared__ u32x4 lds[2][2048];                // 2 x 32 KB
    int tid = threadIdx.x;
    int wid = tid >> 6, lane = tid & 63;
    int stripe = blockIdx.x & 15;
    int rg = blockIdx.x >> 4;                     // 0..63
    int colc = lane & 15;
    int rt0 = rg * 16 + wid * 4;                  // wave's 4 row-tiles (64 rows)

    I16 ah[4][4];
#pragma unroll
    for (int rt = 0; rt < 4; ++rt)
#pragma unroll
        for (int j = 0; j < 4; ++j)
            ah[rt][j].u = ahi4[((size_t)(rt0 + rt) * 4 + j) * 64 + lane];

    unsigned int m1[16], m2[16];
#pragma unroll
    for (int s = 0; s < 16; ++s) { m1[s] = 0xFFFFFFFFu; m2[s] = 0xFFFFFFFFu; }

    i32x4 zc = (i32x4){0, 0, 0, 0};

    auto stage = [&](int ch, int buf) {
        const u32x4* g = bstr + (size_t)(stripe * 4 + ch) * 2048 + tid;
        u32x4* d = &lds[buf][0];
#pragma unroll
        for (int it = 0; it < 8; ++it) {
            __builtin_amdgcn_global_load_lds((const gu32*)(g + it * 256),
                                             (lu32*)(d + it * 256 + tid), 16, 0, 0);
        }
    };

    stage(0, 0);
    __syncthreads();

#pragma unroll
    for (int ch = 0; ch < 4; ++ch) {
        int cur = ch & 1;
        if (ch < 3) stage(ch + 1, cur ^ 1);

        unsigned int ibtv[8];
#pragma unroll
        for (int t = 0; t < 8; ++t)
            ibtv[t] = ibt[stripe * 512 + ch * 128 + t * 16 + colc];

#pragma unroll
        for (int t = 0; t < 8; ++t) {
            i32x4 acc[4];
            {
                I16 bf; bf.u = lds[cur][(t * 4 + 0) * 64 + lane];
#pragma unroll
                for (int rt = 0; rt < 4; ++rt)
                    acc[rt] = __builtin_amdgcn_mfma_i32_16x16x64_i8(ah[rt][0].i, bf.i, zc, 0, 0, 0);
            }
#pragma unroll
            for (int j = 1; j < 4; ++j) {
                I16 bf; bf.u = lds[cur][(t * 4 + j) * 64 + lane];
#pragma unroll
                for (int rt = 0; rt < 4; ++rt)
                    acc[rt] = __builtin_amdgcn_mfma_i32_16x16x64_i8(ah[rt][j].i, bf.i, acc[rt], 0, 0, 0);
            }
#pragma unroll
            for (int rt = 0; rt < 4; ++rt)
#pragma unroll
                for (int r = 0; r < 4; ++r) {
                    unsigned int key = (((unsigned int)acc[rt][r]) << 6) + ibtv[t];
                    int s = rt * 4 + r;
                    m2[s] = umin(umax(key, m1[s]), m2[s]);  // v_med3_u32 (m1<=m2)
                    m1[s] = umin(m1[s], key);
                }
        }
        __syncthreads();                          // joins waves + drains lds DMA
    }

    // tail: per row-slot, top-3 of the 32 (m1,m2) across the 16 lanes sharing
    // the row. key low 6 bits = (code>>4)&31 within stripe.
#pragma unroll
    for (int s = 0; s < 16; ++s) {
        int rt = s >> 2, r = s & 3;
        int row = (rt0 + rt) * 16 + (lane >> 4) * 4 + r;
        unsigned int v0 = m1[s], v1 = m2[s];
        int c0 = stripe * 512 + (int)(v0 & 63) * 16 + colc;
        int c1 = stripe * 512 + (int)(v1 & 63) * 16 + colc;
        int obase = (row * 16 + stripe) * 3;
#pragma unroll
        for (int k = 0; k < 3; ++k) {
            unsigned int bv; int bi;
            if (v1 < v0) { bv = v1; bi = c1; } else { bv = v0; bi = c0; }
#pragma unroll
            for (int mm = 1; mm < 16; mm <<= 1) {
                unsigned int ov = __shfl_xor(bv, mm, 64);
                int oi = __shfl_xor(bi, mm, 64);
                if (ov < bv || (ov == bv && oi < bi)) { bv = ov; bi = oi; }
            }
            if (colc == k) { cd[obase + k] = bv; ci[obase + k] = bi; }
            if (bi == c0) v0 = 0xFFFFFFFFu;
            if (bi == c1) v1 = 0xFFFFFFFFu;
        }
    }
}

// ---------------------------------------------------------------------------
// refine: one wave per row, 48 candidates. Exact np f32 semantics (R2/R3/R4
// verified): f64 dot rounded once, d1 = fl32(z2 - 2*Mf), d2 = fl32(d1 + c2),
// argmin with first-index ties. Window filter on int keys.
// ---------------------------------------------------------------------------
__global__ __launch_bounds__(256)
void refine(const float* __restrict__ zt, const float* __restrict__ z2f,
            const float* __restrict__ cb, const float* __restrict__ c2,
            const unsigned int* __restrict__ cd, const int* __restrict__ ci,
            float* __restrict__ out, int* __restrict__ idxi) {
    int wid = threadIdx.x >> 6, lane = threadIdx.x & 63;
    int n = blockIdx.x * 4 + wid;
    float zq[4];
#pragma unroll
    for (int q = 0; q < 4; ++q) zq[q] = zt[(size_t)n * 256 + q * 64 + lane];
    float z2v = z2f[n];

    unsigned int kd = 0xFFFFFFFFu; int civ = 0;
    if (lane < 48) { kd = cd[n * 48 + lane]; civ = ci[n * 48 + lane]; }
    unsigned int rm = kd;
#pragma unroll
    for (int m = 32; m >= 1; m >>= 1) {
        unsigned int o = __shfl_xor(rm, m, 64);
        rm = o < rm ? o : rm;
    }
    bool active = (lane < 48) && ((kd >> 6) <= (rm >> 6) + WI);
    unsigned long long mask = __ballot(active);
    float bestd = FINF; int besti = 0x7fffffff;
    while (mask) {
        int k = __ffsll(mask) - 1;
        mask &= mask - 1;
        int cidx = __shfl(civ, k, 64);
        const float* crow = cb + (size_t)cidx * 256;
        double dot = 0.0;
#pragma unroll
        for (int q = 0; q < 4; ++q)
            dot += (double)zq[q] * (double)crow[q * 64 + lane];
#pragma unroll
        for (int m = 32; m >= 1; m >>= 1) dot += __shfl_xor(dot, m, 64);
        float Mf = (float)dot;
        float d1 = z2v - 2.0f * Mf;
        float d2 = d1 + c2[cidx];
        if (d2 < bestd || (d2 == bestd && cidx < besti)) { bestd = d2; besti = cidx; }
    }
    if (lane == 0) {
        idxi[n] = besti;
        out[4194304 + n] = (float)besti;
    }
}

// ---------------------------------------------------------------------------
// gather: z_q[b,d,h,w] = codebook[idx[b,h,w]][d], LDS transpose per (b,h)
// ---------------------------------------------------------------------------
__global__ void gather_out(const float* __restrict__ cb,
                           const int* __restrict__ idxi,
                           float* __restrict__ out) {
    __shared__ float tile[32][257];
    __shared__ int sidx[32];
    int b = blockIdx.x >> 5, h = blockIdx.x & 31;
    int tid = threadIdx.x;
    if (tid < 32) sidx[tid] = idxi[(b * 32 + h) * 32 + tid];
    __syncthreads();
    for (int e = tid; e < 8192; e += 256) {
        int w = e >> 8, d = e & 255;
        tile[w][d] = cb[(size_t)sidx[w] * 256 + d];
    }
    __syncthreads();
    for (int e = tid; e < 8192; e += 256) {
        int d = e >> 5, w = e & 31;
        out[(((size_t)b * 256 + d) * 32 + h) * 32 + w] = tile[w][d];
    }
}

// ---------------------------------------------------------------------------
extern "C" void kernel_launch(void* const* d_in, const int* in_sizes, int n_in,
                              void* d_out, int out_size, void* d_ws, size_t ws_size,
                              hipStream_t stream) {
    const float* z  = (const float*)d_in[0];      // [16,256,32,32]
    const float* cb = (const float*)d_in[1];      // [8192,256]
    float* out = (float*)d_out;                   // z_q (4194304) + idx (16384)
    char* w = (char*)d_ws;
    // ws layout (bytes):
    //   ahi   0 .. 4,194,304 (4MB)  [idxi overlaid after vq_main]
    //   bstr  4,194,304 .. 6,291,456 (2MB)
    //   zt    6,291,456 .. 23,068,672 (16MB)
    //   c2 23,068,672 (+32K) | ibt 23,101,440 (+32K) | z2f 23,134,208 (+64K)
    //   cd 23,199,744 (+3M) | ci 26,345,472 (+3M) -> end 29,491,200
    u32x4* ahi  = (u32x4*)(w);
    u32x4* bstr = (u32x4*)(w + 4194304);
    float* zt   = (float*)(w + 6291456);
    float* c2   = (float*)(w + 23068672);
    unsigned int* ibt = (unsigned int*)(w + 23101440);
    float* z2f  = (float*)(w + 23134208);
    unsigned int* cd = (unsigned int*)(w + 23199744);
    int*   ci   = (int*)(w + 26345472);
    int*   idxi = (int*)(w);                      // overlays dead ahi region

    prep_cb<<<512, 256, 0, stream>>>(cb, c2, ibt, bstr);
    prep_z<<<512, 256, 0, stream>>>(z, ahi, zt, z2f);
    vq_main<<<1024, 256, 0, stream>>>(ahi, bstr, ibt, cd, ci);
    refine<<<4096, 256, 0, stream>>>(zt, z2f, cb, c2, cd, ci, out, idxi);
    gather_out<<<512, 256, 0, stream>>>(cb, idxi, out);
}

// Round 6
// 179.604 us; speedup vs baseline: 2.3918x; 2.3918x over previous
//
#include <hip/hip_runtime.h>

typedef __attribute__((ext_vector_type(4))) unsigned int u32x4;
typedef __attribute__((ext_vector_type(4))) int i32x4;

union I16 { u32x4 u; i32x4 i; };

#define SA_INV   (127.0f / 12.0f)           // a = -2z, |a| <= 12 (z tail ~5.2)
#define SB_INV   (127.0f * 8192.0f)         // b in [-1/8192, 1/8192]
#define INV_SASB ((127.0 * 127.0 * 8192.0) / 12.0)   // 1/(sa*sb) ~ 1.101e7
#define WI       4500                        // refine window in int units (~4e-4)
#define FINF     3.4e38f

__device__ __forceinline__ int q8(float x, float s) {
    int q = (int)__builtin_rintf(x * s);
    return q < -127 ? -127 : (q > 127 ? 127 : q);
}
__device__ __forceinline__ unsigned int umin(unsigned int a, unsigned int b) { return a < b ? a : b; }
__device__ __forceinline__ unsigned int umax(unsigned int a, unsigned int b) { return a > b ? a : b; }

// ---------------------------------------------------------------------------
// prep_z: one pass over z -> (1) i8 A fragments (a=-2z quantized),
// (2) zt row-major [16384][256], (3) z2f (f64-accum sum z^2 -> f32).
// A-layout (R4-verified): lane l of row-tile rt, k-step j holds
// A[rt*16+(l&15)][k = j*64 + (l>>4)*16 .. +16], bytes LE = increasing k.
// ---------------------------------------------------------------------------
__global__ __launch_bounds__(256)
void prep_z(const float* __restrict__ z, u32x4* __restrict__ ahi,
            float* __restrict__ zt, float* __restrict__ z2f) {
    __shared__ float tile[32][257];
    __shared__ double pz[32][9];
    int bh = blockIdx.x;                          // 0..511 = b*32+h
    int b = bh >> 5, h = bh & 31;
    int tid = threadIdx.x;
    for (int e = tid; e < 8192; e += 256) {
        int d = e >> 5, w = e & 31;
        tile[w][d] = z[((size_t)(b * 256 + d) * 32 + h) * 32 + w];
    }
    __syncthreads();
    for (int e = tid; e < 8192; e += 256) {
        int w = e >> 8, d = e & 255;
        zt[(size_t)(bh * 32 + w) * 256 + d] = tile[w][d];
    }
    {
        int w = tid >> 3, seg = tid & 7;
        double s = 0.0;
#pragma unroll
        for (int d = 0; d < 32; ++d) { double v = (double)tile[w][seg * 32 + d]; s += v * v; }
        pz[w][seg] = s;
    }
    __syncthreads();
    if (tid < 32) {
        double s = 0.0;
#pragma unroll
        for (int seg = 0; seg < 8; ++seg) s += pz[tid][seg];
        z2f[bh * 32 + tid] = (float)s;
    }
    for (int o = tid; o < 512; o += 256) {        // 2 row-tiles x 4 j x 64 lanes
        int l = o & 63, j = (o >> 6) & 3, tt = o >> 8;
        int wp = tt * 16 + (l & 15);
        int k0 = j * 64 + ((l >> 4) << 4);
        u32x4 v;
#pragma unroll
        for (int d = 0; d < 4; ++d) {
            unsigned int wv = 0;
#pragma unroll
            for (int bb = 0; bb < 4; ++bb) {
                int q = q8(-2.0f * tile[wp][k0 + d * 4 + bb], SA_INV);
                wv |= ((unsigned int)(q & 255)) << (8 * bb);
            }
            v[d] = wv;
        }
        ahi[(size_t)bh * 512 + o] = v;
    }
}

// ---------------------------------------------------------------------------
// prep_cb: one pass over codebook -> (1) i8 B fragments, linear tile order:
// bstr[(ct*4 + j)*64 + l] with code = ct*16 + (l&15), k = j*64+(l>>4)*16..+16;
// (2) c2 (f32); (3) ibt key-bias table. Block = one 16-code tile.
// ---------------------------------------------------------------------------
__global__ __launch_bounds__(256)
void prep_cb(const float* __restrict__ cb, float* __restrict__ c2,
             unsigned int* __restrict__ ibt, u32x4* __restrict__ bstr) {
    __shared__ float tile[16][257];
    __shared__ float pc[16][17];
    int ct = blockIdx.x;                          // 0..511
    int tid = threadIdx.x;
    int cl = tid >> 4, dseg = tid & 15;
    const float* src = cb + (size_t)(ct * 16 + cl) * 256 + dseg * 16;
    float s = 0.f;
#pragma unroll
    for (int i = 0; i < 16; ++i) { float v = src[i]; tile[cl][dseg * 16 + i] = v; s += v * v; }
    pc[cl][dseg] = s;
    __syncthreads();
    if (tid < 16) {
        float t = 0.f;
#pragma unroll
        for (int i = 0; i < 16; ++i) t += pc[tid][i];
        int code = ct * 16 + tid;
        c2[code] = t;
        int ib = (int)__builtin_rintf(t * (float)INV_SASB);
        ibt[code] = (((unsigned int)(ib + 262144)) << 6) | (unsigned int)((code >> 4) & 31);
    }
    int l = tid & 63, j = tid >> 6;
    int code_l = l & 15, k0 = j * 64 + ((l >> 4) << 4);
    u32x4 v;
#pragma unroll
    for (int d = 0; d < 4; ++d) {
        unsigned int wv = 0;
#pragma unroll
        for (int bb = 0; bb < 4; ++bb) {
            int q = q8(tile[code_l][k0 + d * 4 + bb], SB_INV);
            wv |= ((unsigned int)(q & 255)) << (8 * bb);
        }
        v[d] = wv;
    }
    bstr[(size_t)(ct * 4 + j) * 64 + l] = v;
}

// ---------------------------------------------------------------------------
// vq_main: 1024 blocks = 64 rowgroups x 16 stripes; 4 INDEPENDENT waves per
// block (no LDS, no __syncthreads). Wave holds 64 rows of i8 A (64 VGPRs)
// and streams its stripe's 32 code-tiles from L2 straight into VGPRs,
// double-buffered (bfA/bfB). B total = 2 MB -> L2-resident per XCD.
// key = ((acc+bias+2^18)<<6)|tcode; top-2 via min+med3 (3 VALU/value).
// Tail: top-3 per (row,stripe) -> 48 candidates/row.
// ---------------------------------------------------------------------------
__global__ __launch_bounds__(256)
void vq_main(const u32x4* __restrict__ ahi4, const u32x4* __restrict__ bstr,
             const unsigned int* __restrict__ ibt,
             unsigned int* __restrict__ cd, int* __restrict__ ci) {
    int tid = threadIdx.x;
    int wid = tid >> 6, lane = tid & 63;
    int stripe = blockIdx.x & 15;
    int rg = blockIdx.x >> 4;                     // 0..63
    int colc = lane & 15;
    int rt0 = rg * 16 + wid * 4;                  // wave's 4 row-tiles (64 rows)

    I16 ah[4][4];
#pragma unroll
    for (int rt = 0; rt < 4; ++rt)
#pragma unroll
        for (int j = 0; j < 4; ++j)
            ah[rt][j].u = ahi4[((size_t)(rt0 + rt) * 4 + j) * 64 + lane];

    unsigned int m1[16], m2[16];
#pragma unroll
    for (int s = 0; s < 16; ++s) { m1[s] = 0xFFFFFFFFu; m2[s] = 0xFFFFFFFFu; }

    const u32x4* bbase = bstr + (size_t)stripe * 8192 + lane;   // tile t at +t*256
    const unsigned int* ibase = ibt + stripe * 512 + colc;      // tile t at +t*16
    i32x4 zc = (i32x4){0, 0, 0, 0};

    I16 bfA[4], bfB[4];
    unsigned int ibA, ibB;
#pragma unroll
    for (int j = 0; j < 4; ++j) bfA[j].u = bbase[j * 64];
    ibA = ibase[0];

    auto tilework = [&](const I16 (&bf)[4], unsigned int ibv) {
        i32x4 acc[4];
#pragma unroll
        for (int rt = 0; rt < 4; ++rt)
            acc[rt] = __builtin_amdgcn_mfma_i32_16x16x64_i8(ah[rt][0].i, bf[0].i, zc, 0, 0, 0);
#pragma unroll
        for (int j = 1; j < 4; ++j)
#pragma unroll
            for (int rt = 0; rt < 4; ++rt)
                acc[rt] = __builtin_amdgcn_mfma_i32_16x16x64_i8(ah[rt][j].i, bf[j].i, acc[rt], 0, 0, 0);
#pragma unroll
        for (int rt = 0; rt < 4; ++rt)
#pragma unroll
            for (int r = 0; r < 4; ++r) {
                unsigned int key = (((unsigned int)acc[rt][r]) << 6) + ibv;
                int s = rt * 4 + r;
                m2[s] = umin(umax(key, m1[s]), m2[s]);   // v_med3_u32 (m1<=m2)
                m1[s] = umin(m1[s], key);
            }
    };

    for (int t = 0; t < 32; t += 2) {
        // prefetch t+1 (overread past stripe end is harmless: lands in ws)
#pragma unroll
        for (int j = 0; j < 4; ++j) bfB[j].u = bbase[(t + 1) * 256 + j * 64];
        ibB = ibase[(t + 1) * 16];
        tilework(bfA, ibA);
        if (t + 2 < 32) {
#pragma unroll
            for (int j = 0; j < 4; ++j) bfA[j].u = bbase[(t + 2) * 256 + j * 64];
            ibA = ibase[(t + 2) * 16];
        }
        tilework(bfB, ibB);
    }

    // tail: per row-slot, top-3 of the 32 (m1,m2) across the 16 lanes sharing
    // the row (equal lane>>4; xor masks 1,2,4,8 stay in-group).
#pragma unroll
    for (int s = 0; s < 16; ++s) {
        int rt = s >> 2, r = s & 3;
        int row = (rt0 + rt) * 16 + (lane >> 4) * 4 + r;
        unsigned int v0 = m1[s], v1 = m2[s];
        int c0 = stripe * 512 + (int)(v0 & 63) * 16 + colc;
        int c1 = stripe * 512 + (int)(v1 & 63) * 16 + colc;
        int obase = (row * 16 + stripe) * 3;
#pragma unroll
        for (int k = 0; k < 3; ++k) {
            unsigned int bv; int bi;
            if (v1 < v0) { bv = v1; bi = c1; } else { bv = v0; bi = c0; }
#pragma unroll
            for (int mm = 1; mm < 16; mm <<= 1) {
                unsigned int ov = __shfl_xor(bv, mm, 64);
                int oi = __shfl_xor(bi, mm, 64);
                if (ov < bv || (ov == bv && oi < bi)) { bv = ov; bi = oi; }
            }
            if (colc == k) { cd[obase + k] = bv; ci[obase + k] = bi; }
            if (bi == c0) v0 = 0xFFFFFFFFu;
            if (bi == c1) v1 = 0xFFFFFFFFu;
        }
    }
}

// ---------------------------------------------------------------------------
// refine: one wave per row, 48 candidates. Exact np f32 semantics (R2-R5
// verified): f64 dot rounded once, d1 = fl32(z2 - 2*Mf), d2 = fl32(d1 + c2),
// argmin with first-index ties. Window filter on int keys.
// ---------------------------------------------------------------------------
__global__ __launch_bounds__(256)
void refine(const float* __restrict__ zt, const float* __restrict__ z2f,
            const float* __restrict__ cb, const float* __restrict__ c2,
            const unsigned int* __restrict__ cd, const int* __restrict__ ci,
            float* __restrict__ out, int* __restrict__ idxi) {
    int wid = threadIdx.x >> 6, lane = threadIdx.x & 63;
    int n = blockIdx.x * 4 + wid;
    float zq[4];
#pragma unroll
    for (int q = 0; q < 4; ++q) zq[q] = zt[(size_t)n * 256 + q * 64 + lane];
    float z2v = z2f[n];

    unsigned int kd = 0xFFFFFFFFu; int civ = 0;
    if (lane < 48) { kd = cd[n * 48 + lane]; civ = ci[n * 48 + lane]; }
    unsigned int rm = kd;
#pragma unroll
    for (int m = 32; m >= 1; m >>= 1) {
        unsigned int o = __shfl_xor(rm, m, 64);
        rm = o < rm ? o : rm;
    }
    bool active = (lane < 48) && ((kd >> 6) <= (rm >> 6) + WI);
    unsigned long long mask = __ballot(active);
    float bestd = FINF; int besti = 0x7fffffff;
    while (mask) {
        int k = __ffsll(mask) - 1;
        mask &= mask - 1;
        int cidx = __shfl(civ, k, 64);
        const float* crow = cb + (size_t)cidx * 256;
        double dot = 0.0;
#pragma unroll
        for (int q = 0; q < 4; ++q)
            dot += (double)zq[q] * (double)crow[q * 64 + lane];
#pragma unroll
        for (int m = 32; m >= 1; m >>= 1) dot += __shfl_xor(dot, m, 64);
        float Mf = (float)dot;
        float d1 = z2v - 2.0f * Mf;
        float d2 = d1 + c2[cidx];
        if (d2 < bestd || (d2 == bestd && cidx < besti)) { bestd = d2; besti = cidx; }
    }
    if (lane == 0) {
        idxi[n] = besti;
        out[4194304 + n] = (float)besti;
    }
}

// ---------------------------------------------------------------------------
// gather: z_q[b,d,h,w] = codebook[idx[b,h,w]][d], LDS transpose per (b,h)
// ---------------------------------------------------------------------------
__global__ void gather_out(const float* __restrict__ cb,
                           const int* __restrict__ idxi,
                           float* __restrict__ out) {
    __shared__ float tile[32][257];
    __shared__ int sidx[32];
    int b = blockIdx.x >> 5, h = blockIdx.x & 31;
    int tid = threadIdx.x;
    if (tid < 32) sidx[tid] = idxi[(b * 32 + h) * 32 + tid];
    __syncthreads();
    for (int e = tid; e < 8192; e += 256) {
        int w = e >> 8, d = e & 255;
        tile[w][d] = cb[(size_t)sidx[w] * 256 + d];
    }
    __syncthreads();
    for (int e = tid; e < 8192; e += 256) {
        int d = e >> 5, w = e & 31;
        out[(((size_t)b * 256 + d) * 32 + h) * 32 + w] = tile[w][d];
    }
}

// ---------------------------------------------------------------------------
extern "C" void kernel_launch(void* const* d_in, const int* in_sizes, int n_in,
                              void* d_out, int out_size, void* d_ws, size_t ws_size,
                              hipStream_t stream) {
    const float* z  = (const float*)d_in[0];      // [16,256,32,32]
    const float* cb = (const float*)d_in[1];      // [8192,256]
    float* out = (float*)d_out;                   // z_q (4194304) + idx (16384)
    char* w = (char*)d_ws;
    // ws layout (bytes):
    //   ahi   0 .. 4,194,304 (4MB)  [idxi overlaid after vq_main]
    //   bstr  4,194,304 .. 6,291,456 (2MB)
    //   zt    6,291,456 .. 23,068,672 (16MB)
    //   c2 23,068,672 (+32K) | ibt 23,101,440 (+32K) | z2f 23,134,208 (+64K)
    //   cd 23,199,744 (+3M) | ci 26,345,472 (+3M) -> end 29,491,200
    u32x4* ahi  = (u32x4*)(w);
    u32x4* bstr = (u32x4*)(w + 4194304);
    float* zt   = (float*)(w + 6291456);
    float* c2   = (float*)(w + 23068672);
    unsigned int* ibt = (unsigned int*)(w + 23101440);
    float* z2f  = (float*)(w + 23134208);
    unsigned int* cd = (unsigned int*)(w + 23199744);
    int*   ci   = (int*)(w + 26345472);
    int*   idxi = (int*)(w);                      // overlays dead ahi region

    prep_cb<<<512, 256, 0, stream>>>(cb, c2, ibt, bstr);
    prep_z<<<512, 256, 0, stream>>>(z, ahi, zt, z2f);
    vq_main<<<1024, 256, 0, stream>>>(ahi, bstr, ibt, cd, ci);
    refine<<<4096, 256, 0, stream>>>(zt, z2f, cb, c2, cd, ci, out, idxi);
    gather_out<<<512, 256, 0, stream>>>(cb, idxi, out);
}

// Round 7
// 164.675 us; speedup vs baseline: 2.6086x; 1.0907x over previous
//
#include <hip/hip_runtime.h>

typedef __attribute__((ext_vector_type(4))) unsigned int u32x4;
typedef __attribute__((ext_vector_type(4))) int i32x4;

union I16 { u32x4 u; i32x4 i; };

#define SA_INV   (127.0f / 12.0f)           // a = -2z, |a| <= 12 (z tail ~5.2)
#define SB_INV   (127.0f * 8192.0f)         // b in [-1/8192, 1/8192]
#define INV_SASB ((127.0 * 127.0 * 8192.0) / 12.0)   // 1/(sa*sb) ~ 1.101e7
#define WI       4500                        // refine window in int units (~4e-4)
#define FINF     3.4e38f

__device__ __forceinline__ int q8(float x, float s) {
    int q = (int)__builtin_rintf(x * s);
    return q < -127 ? -127 : (q > 127 ? 127 : q);
}

// ---------------------------------------------------------------------------
// prep_z: one pass over z -> (1) i8 A fragments (a=-2z quantized),
// (2) zt row-major [16384][256], (3) z2f (f64-accum sum z^2 -> f32).
// A-layout (R4-verified): lane l of row-tile rt, k-step j holds
// A[rt*16+(l&15)][k = j*64 + (l>>4)*16 .. +16], bytes LE = increasing k.
// ---------------------------------------------------------------------------
__global__ __launch_bounds__(256)
void prep_z(const float* __restrict__ z, u32x4* __restrict__ ahi,
            float* __restrict__ zt, float* __restrict__ z2f) {
    __shared__ float tile[32][257];
    __shared__ double pz[32][9];
    int bh = blockIdx.x;                          // 0..511 = b*32+h
    int b = bh >> 5, h = bh & 31;
    int tid = threadIdx.x;
    for (int e = tid; e < 8192; e += 256) {
        int d = e >> 5, w = e & 31;
        tile[w][d] = z[((size_t)(b * 256 + d) * 32 + h) * 32 + w];
    }
    __syncthreads();
    for (int e = tid; e < 8192; e += 256) {
        int w = e >> 8, d = e & 255;
        zt[(size_t)(bh * 32 + w) * 256 + d] = tile[w][d];
    }
    {
        int w = tid >> 3, seg = tid & 7;
        double s = 0.0;
#pragma unroll
        for (int d = 0; d < 32; ++d) { double v = (double)tile[w][seg * 32 + d]; s += v * v; }
        pz[w][seg] = s;
    }
    __syncthreads();
    if (tid < 32) {
        double s = 0.0;
#pragma unroll
        for (int seg = 0; seg < 8; ++seg) s += pz[tid][seg];
        z2f[bh * 32 + tid] = (float)s;
    }
    for (int o = tid; o < 512; o += 256) {        // 2 row-tiles x 4 j x 64 lanes
        int l = o & 63, j = (o >> 6) & 3, tt = o >> 8;
        int wp = tt * 16 + (l & 15);
        int k0 = j * 64 + ((l >> 4) << 4);
        u32x4 v;
#pragma unroll
        for (int d = 0; d < 4; ++d) {
            unsigned int wv = 0;
#pragma unroll
            for (int bb = 0; bb < 4; ++bb) {
                int q = q8(-2.0f * tile[wp][k0 + d * 4 + bb], SA_INV);
                wv |= ((unsigned int)(q & 255)) << (8 * bb);
            }
            v[d] = wv;
        }
        ahi[(size_t)bh * 512 + o] = v;
    }
}

// ---------------------------------------------------------------------------
// prep_cb: one pass over codebook -> (1) i8 B fragments, linear tile order:
// bstr[(ct*4 + j)*64 + l] with code = ct*16 + (l&15), k = j*64+(l>>4)*16..+16;
// (2) c2 (f32); (3) ibt key-bias table. Block = one 16-code tile.
// ---------------------------------------------------------------------------
__global__ __launch_bounds__(256)
void prep_cb(const float* __restrict__ cb, float* __restrict__ c2,
             unsigned int* __restrict__ ibt, u32x4* __restrict__ bstr) {
    __shared__ float tile[16][257];
    __shared__ float pc[16][17];
    int ct = blockIdx.x;                          // 0..511
    int tid = threadIdx.x;
    int cl = tid >> 4, dseg = tid & 15;
    const float* src = cb + (size_t)(ct * 16 + cl) * 256 + dseg * 16;
    float s = 0.f;
#pragma unroll
    for (int i = 0; i < 16; ++i) { float v = src[i]; tile[cl][dseg * 16 + i] = v; s += v * v; }
    pc[cl][dseg] = s;
    __syncthreads();
    if (tid < 16) {
        float t = 0.f;
#pragma unroll
        for (int i = 0; i < 16; ++i) t += pc[tid][i];
        int code = ct * 16 + tid;
        c2[code] = t;
        int ib = (int)__builtin_rintf(t * (float)INV_SASB);
        ibt[code] = (((unsigned int)(ib + 262144)) << 6) | (unsigned int)((code >> 4) & 31);
    }
    int l = tid & 63, j = tid >> 6;
    int code_l = l & 15, k0 = j * 64 + ((l >> 4) << 4);
    u32x4 v;
#pragma unroll
    for (int d = 0; d < 4; ++d) {
        unsigned int wv = 0;
#pragma unroll
        for (int bb = 0; bb < 4; ++bb) {
            int q = q8(tile[code_l][k0 + d * 4 + bb], SB_INV);
            wv |= ((unsigned int)(q & 255)) << (8 * bb);
        }
        v[d] = wv;
    }
    bstr[(size_t)(ct * 4 + j) * 64 + l] = v;
}

// ---------------------------------------------------------------------------
// vq_main: 2048 blocks = 128 rowgroups x 16 stripes; 4 independent waves per
// block (no LDS, no barriers). Wave holds 32 rows of i8 A (32 VGPRs) and
// streams its stripe's 32 code-tiles from L2 into VGPRs, double-buffered,
// imm-offset addressing via two bumped pointers. Top-2 maintenance is PINNED
// to arch VGPRs via inline asm (4 VALU/value) — R4/R6 showed the compiler
// placing m1/m2/acc in AGPRs and paying ~4x VALU in accvgpr shuttling.
// Tail: top-3 per (row,stripe) -> 48 candidates/row.
// ---------------------------------------------------------------------------
__global__ __launch_bounds__(256)
void vq_main(const u32x4* __restrict__ ahi4, const u32x4* __restrict__ bstr,
             const unsigned int* __restrict__ ibt,
             unsigned int* __restrict__ cd, int* __restrict__ ci) {
    int tid = threadIdx.x;
    int wid = tid >> 6, lane = tid & 63;
    int stripe = blockIdx.x & 15;
    int rg = blockIdx.x >> 4;                     // 0..127
    int colc = lane & 15;
    int rt0 = rg * 8 + wid * 2;                   // wave's 2 row-tiles (32 rows)

    I16 ah[2][4];
#pragma unroll
    for (int rt = 0; rt < 2; ++rt)
#pragma unroll
        for (int j = 0; j < 4; ++j)
            ah[rt][j].u = ahi4[((size_t)(rt0 + rt) * 4 + j) * 64 + lane];

    unsigned int m1[8], m2[8];
#pragma unroll
    for (int s = 0; s < 8; ++s) { m1[s] = 0xFFFFFFFFu; m2[s] = 0xFFFFFFFFu; }

    const u32x4* p0 = bstr + (size_t)stripe * 8192 + lane;        // even tiles
    const u32x4* p1 = p0 + 256;                                   // odd tiles
    const unsigned int* ip = ibt + stripe * 512 + colc;
    i32x4 zc = (i32x4){0, 0, 0, 0};

    I16 bfA[4], bfB[4];
    unsigned int ibA, ibB;
#pragma unroll
    for (int j = 0; j < 4; ++j) bfA[j].u = p0[j * 64];
    ibA = ip[0];

    auto tilework = [&](const I16 (&bf)[4], unsigned int ibv) {
        i32x4 acc0, acc1;
        acc0 = __builtin_amdgcn_mfma_i32_16x16x64_i8(ah[0][0].i, bf[0].i, zc, 0, 0, 0);
        acc1 = __builtin_amdgcn_mfma_i32_16x16x64_i8(ah[1][0].i, bf[0].i, zc, 0, 0, 0);
#pragma unroll
        for (int j = 1; j < 4; ++j) {
            acc0 = __builtin_amdgcn_mfma_i32_16x16x64_i8(ah[0][j].i, bf[j].i, acc0, 0, 0, 0);
            acc1 = __builtin_amdgcn_mfma_i32_16x16x64_i8(ah[1][j].i, bf[j].i, acc1, 0, 0, 0);
        }
#pragma unroll
        for (int s = 0; s < 8; ++s) {
            unsigned int av = (unsigned int)((s < 4) ? acc0[s & 3] : acc1[s & 3]);
            unsigned int key, tmp;
            // key = (acc<<6) + ibv ; tmp = max(key,m1); m2 = min(m2,tmp);
            // m1 = min(m1,key).  "v" constraints pin all to arch VGPRs.
            asm("v_lshl_add_u32 %0, %4, 6, %5\n\t"
                "v_max_u32 %1, %0, %2\n\t"
                "v_min_u32 %3, %3, %1\n\t"
                "v_min_u32 %2, %2, %0"
                : "=&v"(key), "=&v"(tmp), "+v"(m1[s]), "+v"(m2[s])
                : "v"(av), "v"(ibv));
        }
    };

    for (int t = 0; t < 32; t += 2) {
#pragma unroll
        for (int j = 0; j < 4; ++j) bfB[j].u = p1[j * 64];        // prefetch t+1
        ibB = ip[(t + 1) * 16];
        tilework(bfA, ibA);
        if (t + 2 < 32) {
            p0 += 512;
#pragma unroll
            for (int j = 0; j < 4; ++j) bfA[j].u = p0[j * 64];    // prefetch t+2
            ibA = ip[(t + 2) * 16];
        }
        tilework(bfB, ibB);
        p1 += 512;
    }

    // tail: per row-slot, top-3 of the 16 (m1,m2) across the 16 lanes sharing
    // the row (equal lane>>4; xor masks 1,2,4,8 stay in-group).
#pragma unroll
    for (int s = 0; s < 8; ++s) {
        int rt = s >> 2, r = s & 3;
        int row = (rt0 + rt) * 16 + (lane >> 4) * 4 + r;
        unsigned int v0 = m1[s], v1 = m2[s];
        int c0 = stripe * 512 + (int)(v0 & 63) * 16 + colc;
        int c1 = stripe * 512 + (int)(v1 & 63) * 16 + colc;
        int obase = (row * 16 + stripe) * 3;
#pragma unroll
        for (int k = 0; k < 3; ++k) {
            unsigned int bv; int bi;
            if (v1 < v0) { bv = v1; bi = c1; } else { bv = v0; bi = c0; }
#pragma unroll
            for (int mm = 1; mm < 16; mm <<= 1) {
                unsigned int ov = __shfl_xor(bv, mm, 64);
                int oi = __shfl_xor(bi, mm, 64);
                if (ov < bv || (ov == bv && oi < bi)) { bv = ov; bi = oi; }
            }
            if (colc == k) { cd[obase + k] = bv; ci[obase + k] = bi; }
            if (bi == c0) v0 = 0xFFFFFFFFu;
            if (bi == c1) v1 = 0xFFFFFFFFu;
        }
    }
}

// ---------------------------------------------------------------------------
// refine: one wave per row, 48 candidates. Exact np f32 semantics (R2-R6
// verified): f64 dot rounded once, d1 = fl32(z2 - 2*Mf), d2 = fl32(d1 + c2),
// argmin with first-index ties. Window filter on int keys.
// ---------------------------------------------------------------------------
__global__ __launch_bounds__(256)
void refine(const float* __restrict__ zt, const float* __restrict__ z2f,
            const float* __restrict__ cb, const float* __restrict__ c2,
            const unsigned int* __restrict__ cd, const int* __restrict__ ci,
            float* __restrict__ out, int* __restrict__ idxi) {
    int wid = threadIdx.x >> 6, lane = threadIdx.x & 63;
    int n = blockIdx.x * 4 + wid;
    float zq[4];
#pragma unroll
    for (int q = 0; q < 4; ++q) zq[q] = zt[(size_t)n * 256 + q * 64 + lane];
    float z2v = z2f[n];

    unsigned int kd = 0xFFFFFFFFu; int civ = 0;
    if (lane < 48) { kd = cd[n * 48 + lane]; civ = ci[n * 48 + lane]; }
    unsigned int rm = kd;
#pragma unroll
    for (int m = 32; m >= 1; m >>= 1) {
        unsigned int o = __shfl_xor(rm, m, 64);
        rm = o < rm ? o : rm;
    }
    bool active = (lane < 48) && ((kd >> 6) <= (rm >> 6) + WI);
    unsigned long long mask = __ballot(active);
    float bestd = FINF; int besti = 0x7fffffff;
    while (mask) {
        int k = __ffsll(mask) - 1;
        mask &= mask - 1;
        int cidx = __shfl(civ, k, 64);
        const float* crow = cb + (size_t)cidx * 256;
        double dot = 0.0;
#pragma unroll
        for (int q = 0; q < 4; ++q)
            dot += (double)zq[q] * (double)crow[q * 64 + lane];
#pragma unroll
        for (int m = 32; m >= 1; m >>= 1) dot += __shfl_xor(dot, m, 64);
        float Mf = (float)dot;
        float d1 = z2v - 2.0f * Mf;
        float d2 = d1 + c2[cidx];
        if (d2 < bestd || (d2 == bestd && cidx < besti)) { bestd = d2; besti = cidx; }
    }
    if (lane == 0) {
        idxi[n] = besti;
        out[4194304 + n] = (float)besti;
    }
}

// ---------------------------------------------------------------------------
// gather: z_q[b,d,h,w] = codebook[idx[b,h,w]][d], LDS transpose per (b,h)
// ---------------------------------------------------------------------------
__global__ void gather_out(const float* __restrict__ cb,
                           const int* __restrict__ idxi,
                           float* __restrict__ out) {
    __shared__ float tile[32][257];
    __shared__ int sidx[32];
    int b = blockIdx.x >> 5, h = blockIdx.x & 31;
    int tid = threadIdx.x;
    if (tid < 32) sidx[tid] = idxi[(b * 32 + h) * 32 + tid];
    __syncthreads();
    for (int e = tid; e < 8192; e += 256) {
        int w = e >> 8, d = e & 255;
        tile[w][d] = cb[(size_t)sidx[w] * 256 + d];
    }
    __syncthreads();
    for (int e = tid; e < 8192; e += 256) {
        int d = e >> 5, w = e & 31;
        out[(((size_t)b * 256 + d) * 32 + h) * 32 + w] = tile[w][d];
    }
}

// ---------------------------------------------------------------------------
extern "C" void kernel_launch(void* const* d_in, const int* in_sizes, int n_in,
                              void* d_out, int out_size, void* d_ws, size_t ws_size,
                              hipStream_t stream) {
    const float* z  = (const float*)d_in[0];      // [16,256,32,32]
    const float* cb = (const float*)d_in[1];      // [8192,256]
    float* out = (float*)d_out;                   // z_q (4194304) + idx (16384)
    char* w = (char*)d_ws;
    // ws layout (bytes):
    //   ahi   0 .. 4,194,304 (4MB)  [idxi overlaid after vq_main]
    //   bstr  4,194,304 .. 6,291,456 (2MB)
    //   zt    6,291,456 .. 23,068,672 (16MB)
    //   c2 23,068,672 (+32K) | ibt 23,101,440 (+32K) | z2f 23,134,208 (+64K)
    //   cd 23,199,744 (+3M) | ci 26,345,472 (+3M) -> end 29,491,200
    u32x4* ahi  = (u32x4*)(w);
    u32x4* bstr = (u32x4*)(w + 4194304);
    float* zt   = (float*)(w + 6291456);
    float* c2   = (float*)(w + 23068672);
    unsigned int* ibt = (unsigned int*)(w + 23101440);
    float* z2f  = (float*)(w + 23134208);
    unsigned int* cd = (unsigned int*)(w + 23199744);
    int*   ci   = (int*)(w + 26345472);
    int*   idxi = (int*)(w);                      // overlays dead ahi region

    prep_cb<<<512, 256, 0, stream>>>(cb, c2, ibt, bstr);
    prep_z<<<512, 256, 0, stream>>>(z, ahi, zt, z2f);
    vq_main<<<2048, 256, 0, stream>>>(ahi, bstr, ibt, cd, ci);
    refine<<<4096, 256, 0, stream>>>(zt, z2f, cb, c2, cd, ci, out, idxi);
    gather_out<<<512, 256, 0, stream>>>(cb, idxi, out);
}

// Round 9
// 161.382 us; speedup vs baseline: 2.6619x; 1.0204x over previous
//
#include <hip/hip_runtime.h>

typedef __attribute__((ext_vector_type(4))) unsigned int u32x4;
typedef __attribute__((ext_vector_type(4))) int i32x4;

union I16 { u32x4 u; i32x4 i; };

#define SA_INV   (127.0f / 12.0f)           // a = -2z, |a| <= 12 (z tail ~5.2)
#define SB_INV   (127.0f * 8192.0f)         // b in [-1/8192, 1/8192]
#define INV_SASB ((127.0 * 127.0 * 8192.0) / 12.0)   // 1/(sa*sb) ~ 1.101e7
#define WI       4500                        // refine window in int units (~4e-4)
#define FINF     3.4e38f

__device__ __forceinline__ int q8(float x, float s) {
    int q = (int)__builtin_rintf(x * s);
    return q < -127 ? -127 : (q > 127 ? 127 : q);
}

// ---------------------------------------------------------------------------
// prep_all: blocks 0..511 process the codebook (i8 B fragments in linear tile
// order, c2, ibt); blocks 512..1023 process z (i8 A fragments scaled by -2,
// zt row-major, z2f). Faithful merge of R7's prep_cb/prep_z (under bisect).
// ---------------------------------------------------------------------------
__global__ __launch_bounds__(256)
void prep_all(const float* __restrict__ z, const float* __restrict__ cb,
              u32x4* __restrict__ ahi, float* __restrict__ zt,
              float* __restrict__ z2f, float* __restrict__ c2,
              unsigned int* __restrict__ ibt, u32x4* __restrict__ bstr) {
    __shared__ double pzbuf[32 * 9];              // doubles / pc floats
    __shared__ float tile[32 * 257];
    int tid = threadIdx.x;
    if (blockIdx.x < 512) {
        // ---- codebook path: one 16-code tile per block ----
        float* t16 = tile;                        // [16][257]
        float* pc = (float*)pzbuf;                // [16][17]
        int ct = blockIdx.x;
        int cl = tid >> 4, dseg = tid & 15;
        const float* src = cb + (size_t)(ct * 16 + cl) * 256 + dseg * 16;
        float s = 0.f;
#pragma unroll
        for (int i = 0; i < 16; ++i) { float v = src[i]; t16[cl * 257 + dseg * 16 + i] = v; s += v * v; }
        pc[cl * 17 + dseg] = s;
        __syncthreads();
        if (tid < 16) {
            float t = 0.f;
#pragma unroll
            for (int i = 0; i < 16; ++i) t += pc[tid * 17 + i];
            int code = ct * 16 + tid;
            c2[code] = t;
            int ib = (int)__builtin_rintf(t * (float)INV_SASB);
            ibt[code] = (((unsigned int)(ib + 262144)) << 6) | (unsigned int)((code >> 4) & 31);
        }
        int l = tid & 63, j = tid >> 6;
        int code_l = l & 15, k0 = j * 64 + ((l >> 4) << 4);
        u32x4 v;
#pragma unroll
        for (int d = 0; d < 4; ++d) {
            unsigned int wv = 0;
#pragma unroll
            for (int bb = 0; bb < 4; ++bb) {
                int q = q8(t16[code_l * 257 + k0 + d * 4 + bb], SB_INV);
                wv |= ((unsigned int)(q & 255)) << (8 * bb);
            }
            v[d] = wv;
        }
        bstr[(size_t)(ct * 4 + j) * 64 + l] = v;
    } else {
        // ---- z path: one (b,h) pair per block ----
        int bh = blockIdx.x - 512;                // 0..511
        int b = bh >> 5, h = bh & 31;
        for (int e = tid; e < 8192; e += 256) {
            int d = e >> 5, w = e & 31;
            tile[w * 257 + d] = z[((size_t)(b * 256 + d) * 32 + h) * 32 + w];
        }
        __syncthreads();
        for (int e = tid; e < 8192; e += 256) {
            int w = e >> 8, d = e & 255;
            zt[(size_t)(bh * 32 + w) * 256 + d] = tile[w * 257 + d];
        }
        {
            int w = tid >> 3, seg = tid & 7;
            double s = 0.0;
#pragma unroll
            for (int d = 0; d < 32; ++d) { double v = (double)tile[w * 257 + seg * 32 + d]; s += v * v; }
            pzbuf[w * 9 + seg] = s;
        }
        __syncthreads();
        if (tid < 32) {
            double s = 0.0;
#pragma unroll
            for (int seg = 0; seg < 8; ++seg) s += pzbuf[tid * 9 + seg];
            z2f[bh * 32 + tid] = (float)s;
        }
        for (int o = tid; o < 512; o += 256) {    // 2 row-tiles x 4 j x 64 lanes
            int l = o & 63, j = (o >> 6) & 3, tt = o >> 8;
            int wp = tt * 16 + (l & 15);
            int k0 = j * 64 + ((l >> 4) << 4);
            u32x4 v;
#pragma unroll
            for (int d = 0; d < 4; ++d) {
                unsigned int wv = 0;
#pragma unroll
                for (int bb = 0; bb < 4; ++bb) {
                    int q = q8(-2.0f * tile[wp * 257 + k0 + d * 4 + bb], SA_INV);
                    wv |= ((unsigned int)(q & 255)) << (8 * bb);
                }
                v[d] = wv;
            }
            ahi[(size_t)bh * 512 + o] = v;
        }
    }
}

// ---------------------------------------------------------------------------
// vq_main: R7-EXACT (known good, 71 µs). 2048 blocks = 128 rowgroups x 16
// stripes; 4 independent waves/block, no LDS/barriers. Wave holds 32 rows of
// i8 A, streams 32 code-tiles from L2, double-buffered, asm-pinned top-2.
// NO launch_bounds cap: R8's (256,4) cap produced wrong results (integer
// pipeline is exact, so wrong-output == miscompile around spill/asm/MFMA).
// ---------------------------------------------------------------------------
__global__ __launch_bounds__(256)
void vq_main(const u32x4* __restrict__ ahi4, const u32x4* __restrict__ bstr,
             const unsigned int* __restrict__ ibt,
             unsigned int* __restrict__ cd, int* __restrict__ ci) {
    int tid = threadIdx.x;
    int wid = tid >> 6, lane = tid & 63;
    int stripe = blockIdx.x & 15;
    int rg = blockIdx.x >> 4;                     // 0..127
    int colc = lane & 15;
    int rt0 = rg * 8 + wid * 2;                   // wave's 2 row-tiles (32 rows)

    I16 ah[2][4];
#pragma unroll
    for (int rt = 0; rt < 2; ++rt)
#pragma unroll
        for (int j = 0; j < 4; ++j)
            ah[rt][j].u = ahi4[((size_t)(rt0 + rt) * 4 + j) * 64 + lane];

    unsigned int m1[8], m2[8];
#pragma unroll
    for (int s = 0; s < 8; ++s) { m1[s] = 0xFFFFFFFFu; m2[s] = 0xFFFFFFFFu; }

    const u32x4* p0 = bstr + (size_t)stripe * 8192 + lane;        // even tiles
    const u32x4* p1 = p0 + 256;                                   // odd tiles
    const unsigned int* ip = ibt + stripe * 512 + colc;
    i32x4 zc = (i32x4){0, 0, 0, 0};

    I16 bfA[4], bfB[4];
    unsigned int ibA, ibB;
#pragma unroll
    for (int j = 0; j < 4; ++j) bfA[j].u = p0[j * 64];
    ibA = ip[0];

    auto tilework = [&](const I16 (&bf)[4], unsigned int ibv) {
        i32x4 acc0, acc1;
        acc0 = __builtin_amdgcn_mfma_i32_16x16x64_i8(ah[0][0].i, bf[0].i, zc, 0, 0, 0);
        acc1 = __builtin_amdgcn_mfma_i32_16x16x64_i8(ah[1][0].i, bf[0].i, zc, 0, 0, 0);
#pragma unroll
        for (int j = 1; j < 4; ++j) {
            acc0 = __builtin_amdgcn_mfma_i32_16x16x64_i8(ah[0][j].i, bf[j].i, acc0, 0, 0, 0);
            acc1 = __builtin_amdgcn_mfma_i32_16x16x64_i8(ah[1][j].i, bf[j].i, acc1, 0, 0, 0);
        }
#pragma unroll
        for (int s = 0; s < 8; ++s) {
            unsigned int av = (unsigned int)((s < 4) ? acc0[s & 3] : acc1[s & 3]);
            unsigned int key, tmp;
            asm("v_lshl_add_u32 %0, %4, 6, %5\n\t"
                "v_max_u32 %1, %0, %2\n\t"
                "v_min_u32 %3, %3, %1\n\t"
                "v_min_u32 %2, %2, %0"
                : "=&v"(key), "=&v"(tmp), "+v"(m1[s]), "+v"(m2[s])
                : "v"(av), "v"(ibv));
        }
    };

    for (int t = 0; t < 32; t += 2) {
#pragma unroll
        for (int j = 0; j < 4; ++j) bfB[j].u = p1[j * 64];        // prefetch t+1
        ibB = ip[(t + 1) * 16];
        tilework(bfA, ibA);
        if (t + 2 < 32) {
            p0 += 512;
#pragma unroll
            for (int j = 0; j < 4; ++j) bfA[j].u = p0[j * 64];    // prefetch t+2
            ibA = ip[(t + 2) * 16];
        }
        tilework(bfB, ibB);
        p1 += 512;
    }

    // tail: per row-slot, top-3 of the 16 (m1,m2) across the 16 lanes sharing
    // the row (equal lane>>4; xor masks 1,2,4,8 stay in-group).
#pragma unroll
    for (int s = 0; s < 8; ++s) {
        int rt = s >> 2, r = s & 3;
        int row = (rt0 + rt) * 16 + (lane >> 4) * 4 + r;
        unsigned int v0 = m1[s], v1 = m2[s];
        int c0 = stripe * 512 + (int)(v0 & 63) * 16 + colc;
        int c1 = stripe * 512 + (int)(v1 & 63) * 16 + colc;
        int obase = (row * 16 + stripe) * 3;
#pragma unroll
        for (int k = 0; k < 3; ++k) {
            unsigned int bv; int bi;
            if (v1 < v0) { bv = v1; bi = c1; } else { bv = v0; bi = c0; }
#pragma unroll
            for (int mm = 1; mm < 16; mm <<= 1) {
                unsigned int ov = __shfl_xor(bv, mm, 64);
                int oi = __shfl_xor(bi, mm, 64);
                if (ov < bv || (ov == bv && oi < bi)) { bv = ov; bi = oi; }
            }
            if (colc == k) { cd[obase + k] = bv; ci[obase + k] = bi; }
            if (bi == c0) v0 = 0xFFFFFFFFu;
            if (bi == c1) v1 = 0xFFFFFFFFu;
        }
    }
}

// ---------------------------------------------------------------------------
// refine: one wave per row, 48 candidates. Exact np f32 semantics (R2-R7
// verified): f64 dot rounded once, d1 = fl32(z2 - 2*Mf), d2 = fl32(d1 + c2),
// argmin with first-index ties. Window filter on int keys.
// ---------------------------------------------------------------------------
__global__ __launch_bounds__(256)
void refine(const float* __restrict__ zt, const float* __restrict__ z2f,
            const float* __restrict__ cb, const float* __restrict__ c2,
            const unsigned int* __restrict__ cd, const int* __restrict__ ci,
            float* __restrict__ out, int* __restrict__ idxi) {
    int wid = threadIdx.x >> 6, lane = threadIdx.x & 63;
    int n = blockIdx.x * 4 + wid;
    float zq[4];
#pragma unroll
    for (int q = 0; q < 4; ++q) zq[q] = zt[(size_t)n * 256 + q * 64 + lane];
    float z2v = z2f[n];

    unsigned int kd = 0xFFFFFFFFu; int civ = 0;
    if (lane < 48) { kd = cd[n * 48 + lane]; civ = ci[n * 48 + lane]; }
    unsigned int rm = kd;
#pragma unroll
    for (int m = 32; m >= 1; m >>= 1) {
        unsigned int o = __shfl_xor(rm, m, 64);
        rm = o < rm ? o : rm;
    }
    bool active = (lane < 48) && ((kd >> 6) <= (rm >> 6) + WI);
    unsigned long long mask = __ballot(active);
    float bestd = FINF; int besti = 0x7fffffff;
    while (mask) {
        int k = __ffsll(mask) - 1;
        mask &= mask - 1;
        int cidx = __shfl(civ, k, 64);
        const float* crow = cb + (size_t)cidx * 256;
        double dot = 0.0;
#pragma unroll
        for (int q = 0; q < 4; ++q)
            dot += (double)zq[q] * (double)crow[q * 64 + lane];
#pragma unroll
        for (int m = 32; m >= 1; m >>= 1) dot += __shfl_xor(dot, m, 64);
        float Mf = (float)dot;
        float d1 = z2v - 2.0f * Mf;
        float d2 = d1 + c2[cidx];
        if (d2 < bestd || (d2 == bestd && cidx < besti)) { bestd = d2; besti = cidx; }
    }
    if (lane == 0) {
        idxi[n] = besti;
        out[4194304 + n] = (float)besti;
    }
}

// ---------------------------------------------------------------------------
// gather: z_q[b,d,h,w] = codebook[idx[b,h,w]][d], LDS transpose per (b,h)
// ---------------------------------------------------------------------------
__global__ void gather_out(const float* __restrict__ cb,
                           const int* __restrict__ idxi,
                           float* __restrict__ out) {
    __shared__ float tile[32][257];
    __shared__ int sidx[32];
    int b = blockIdx.x >> 5, h = blockIdx.x & 31;
    int tid = threadIdx.x;
    if (tid < 32) sidx[tid] = idxi[(b * 32 + h) * 32 + tid];
    __syncthreads();
    for (int e = tid; e < 8192; e += 256) {
        int w = e >> 8, d = e & 255;
        tile[w][d] = cb[(size_t)sidx[w] * 256 + d];
    }
    __syncthreads();
    for (int e = tid; e < 8192; e += 256) {
        int d = e >> 5, w = e & 31;
        out[(((size_t)b * 256 + d) * 32 + h) * 32 + w] = tile[w][d];
    }
}

// ---------------------------------------------------------------------------
extern "C" void kernel_launch(void* const* d_in, const int* in_sizes, int n_in,
                              void* d_out, int out_size, void* d_ws, size_t ws_size,
                              hipStream_t stream) {
    const float* z  = (const float*)d_in[0];      // [16,256,32,32]
    const float* cb = (const float*)d_in[1];      // [8192,256]
    float* out = (float*)d_out;                   // z_q (4194304) + idx (16384)
    char* w = (char*)d_ws;
    // ws layout (bytes):
    //   ahi   0 .. 4,194,304 (4MB)  [idxi overlaid after vq_main]
    //   bstr  4,194,304 .. 6,291,456 (2MB)
    //   zt    6,291,456 .. 23,068,672 (16MB)
    //   c2 23,068,672 (+32K) | ibt 23,101,440 (+32K) | z2f 23,134,208 (+64K)
    //   cd 23,199,744 (+3M) | ci 26,345,472 (+3M) -> end 29,491,200
    u32x4* ahi  = (u32x4*)(w);
    u32x4* bstr = (u32x4*)(w + 4194304);
    float* zt   = (float*)(w + 6291456);
    float* c2   = (float*)(w + 23068672);
    unsigned int* ibt = (unsigned int*)(w + 23101440);
    float* z2f  = (float*)(w + 23134208);
    unsigned int* cd = (unsigned int*)(w + 23199744);
    int*   ci   = (int*)(w + 26345472);
    int*   idxi = (int*)(w);                      // overlays dead ahi region

    prep_all<<<1024, 256, 0, stream>>>(z, cb, ahi, zt, z2f, c2, ibt, bstr);
    vq_main<<<2048, 256, 0, stream>>>(ahi, bstr, ibt, cd, ci);
    refine<<<4096, 256, 0, stream>>>(zt, z2f, cb, c2, cd, ci, out, idxi);
    gather_out<<<512, 256, 0, stream>>>(cb, idxi, out);
}